// Round 8
// baseline (524.970 us; speedup 1.0000x reference)
//
#include <hip/hip_runtime.h>
#include <hip/hip_bf16.h>
#include <stdint.h>

typedef __hip_bfloat16 bf16;
typedef __attribute__((ext_vector_type(8))) short bf16x8;
typedef __attribute__((ext_vector_type(4))) float f32x4;

#define VOCABN 100000
#define EDIM 128
#define BN 16
#define SN 2048
#define GRID 256
#define TPB 512
#define NWAVE (GRID * 8)   // 2048 global waves
#define NT 6250            // 16-row tiles in vocab

// ws float offsets
#define CTR_OFF 0        // 16 u32 barrier counters (memset to 0 each launch)
#define PS_OFF  64       // 512  (psum[16][32])
#define U0_OFF  576      // 2048
#define U1_OFF  2624     // 2048
#define U2_OFF  4672     // 2048
#define PBV_OFF 6720     // 1200
#define PBI_OFF 7920     // 1200
#define DT_OFF  16384    // 1,600,000 (D^T [100000][16])
#define WT_OFF  1616384  // 1,600,000 (wt  [100000][16])
#define DUP_OFF 3216384  // 256*2048 du partials

// ---------- device-coherent scalar access (bypasses non-coherent XCD L2) ----------
__device__ inline void scstore(float* p, float v) {
  __hip_atomic_store(p, v, __ATOMIC_RELAXED, __HIP_MEMORY_SCOPE_AGENT);
}
__device__ inline float scload(const float* p) {
  return __hip_atomic_load(p, __ATOMIC_RELAXED, __HIP_MEMORY_SCOPE_AGENT);
}
__device__ inline void scstore_i(int* p, int v) {
  __hip_atomic_store(p, v, __ATOMIC_RELAXED, __HIP_MEMORY_SCOPE_AGENT);
}
__device__ inline int scload_i(const int* p) {
  return __hip_atomic_load(p, __ATOMIC_RELAXED, __HIP_MEMORY_SCOPE_AGENT);
}

// ---------- threefry2x32 (JAX partitionable) ----------
__host__ __device__ inline void tf2x32(uint32_t k0, uint32_t k1,
                                       uint32_t x0, uint32_t x1,
                                       uint32_t* o0, uint32_t* o1) {
  const uint32_t rotA[4] = {13u, 15u, 26u, 6u};
  const uint32_t rotB[4] = {17u, 29u, 16u, 24u};
  uint32_t ks0 = k0, ks1 = k1, ks2 = k0 ^ k1 ^ 0x1BD11BDAu;
  x0 += ks0; x1 += ks1;
#pragma unroll
  for (int g = 0; g < 5; ++g) {
    const uint32_t* r = (g & 1) ? rotB : rotA;
#pragma unroll
    for (int i = 0; i < 4; ++i) {
      x0 += x1;
      x1 = (x1 << r[i]) | (x1 >> (32u - r[i]));
      x1 ^= x0;
    }
    uint32_t a0 = (g % 3 == 0) ? ks1 : ((g % 3 == 1) ? ks2 : ks0);
    uint32_t a1 = (g % 3 == 0) ? ks2 : ((g % 3 == 1) ? ks0 : ks1);
    x0 += a0;
    x1 += a1 + (uint32_t)(g + 1);
  }
  *o0 = x0; *o1 = x1;
}

__device__ inline uint16_t f2bu(float f) {
  bf16 h = __float2bfloat16(f);
  uint16_t u; __builtin_memcpy(&u, &h, 2); return u;
}
__device__ inline float gumbel(uint32_t ka, uint32_t kb, uint32_t flat) {
  uint32_t o0, o1;
  tf2x32(ka, kb, 0u, flat, &o0, &o1);
  uint32_t bits = o0 ^ o1;
  float u0 = __uint_as_float((bits >> 9) | 0x3f800000u) - 1.0f;
  float uu = fmaxf(1e-10f, u0 + 1e-10f);
  return -logf(-logf(uu));
}

// ---------- grid barrier: NO fences — all cross-phase data is sc-coherent ----------
__device__ inline void gbar(uint32_t* ctr) {
  asm volatile("s_waitcnt vmcnt(0) lgkmcnt(0)" ::: "memory");  // my stores at coherence pt
  __syncthreads();
  if (threadIdx.x == 0) {
    __hip_atomic_fetch_add(ctr, 1u, __ATOMIC_RELAXED, __HIP_MEMORY_SCOPE_AGENT);
    while (__hip_atomic_load(ctr, __ATOMIC_RELAXED, __HIP_MEMORY_SCOPE_AGENT)
           < (uint32_t)GRID)
      __builtin_amdgcn_s_sleep(8);
  }
  __syncthreads();
}

// ---------- u (global, sc) -> LDS pool ----------
__device__ inline void load_u_lds(const float* ug, float* pool) {
  for (int i = threadIdx.x; i < 2048; i += TPB) pool[i] = scload(ug + i);
  __syncthreads();
}

// ---------- one 16-row MFMA tile (R3/R7-verified fragment scheme) ----------
__device__ inline void mfma_tile(const float4* ar, const bf16x8* Bhi,
                                 const bf16x8* Blo, float* __restrict__ Dt,
                                 int v0, int n, int q) {
  f32x4 acc = {0.f, 0.f, 0.f, 0.f};
#pragma unroll
  for (int kk = 0; kk < 4; ++kk) {
    float4 a0 = ar[2 * kk], a1 = ar[2 * kk + 1];
    bf16x8 A;
    A[0] = (short)f2bu(a0.x); A[1] = (short)f2bu(a0.y);
    A[2] = (short)f2bu(a0.z); A[3] = (short)f2bu(a0.w);
    A[4] = (short)f2bu(a1.x); A[5] = (short)f2bu(a1.y);
    A[6] = (short)f2bu(a1.z); A[7] = (short)f2bu(a1.w);
    acc = __builtin_amdgcn_mfma_f32_16x16x32_bf16(A, Bhi[kk], acc, 0, 0, 0);
    acc = __builtin_amdgcn_mfma_f32_16x16x32_bf16(A, Blo[kk], acc, 0, 0, 0);
  }
#pragma unroll
  for (int j = 0; j < 4; ++j)
    scstore(Dt + (size_t)(v0 + q * 4 + j) * 16 + n, acc[j]);
}

// ---------- D-pass: depth-3 tile pipeline; u from LDS pool ----------
__device__ void phase_D(const float* __restrict__ Ct, const float* pool,
                        float* __restrict__ Dt, float* __restrict__ wtz, int gw) {
  const int lane = threadIdx.x & 63;
  const int n = lane & 15, q = lane >> 4;
  if (wtz) {
    for (int i = blockIdx.x * TPB + threadIdx.x; i < VOCABN * 16; i += GRID * TPB)
      scstore(wtz + i, 0.f);
  }
  bf16x8 Bhi[4], Blo[4];
#pragma unroll
  for (int kk = 0; kk < 4; ++kk) {
    const float* up = pool + n * EDIM + kk * 32 + q * 8;
    float4 x0 = *(const float4*)up, x1 = *(const float4*)(up + 4);
    float xs[8] = {x0.x, x0.y, x0.z, x0.w, x1.x, x1.y, x1.z, x1.w};
#pragma unroll
    for (int i = 0; i < 8; ++i) {
      uint16_t hbv = f2bu(xs[i]);
      float hf = __uint_as_float((uint32_t)hbv << 16);
      Bhi[kk][i] = (short)hbv;
      Blo[kk][i] = (short)f2bu(xs[i] - hf);
    }
  }
  for (int t0 = gw; t0 < NT; t0 += 3 * NWAVE) {
    const int tA = t0, tB = t0 + NWAVE, tC = t0 + 2 * NWAVE;
    const bool hB = (tB < NT), hC = (tC < NT);
    float4 a[8], b[8], c[8];
    {
      const float* ap = Ct + (size_t)(tA * 16 + n) * EDIM + q * 8;
#pragma unroll
      for (int kk = 0; kk < 4; ++kk) {
        a[2 * kk]     = *(const float4*)(ap + kk * 32);
        a[2 * kk + 1] = *(const float4*)(ap + kk * 32 + 4);
      }
    }
    if (hB) {
      const float* bp = Ct + (size_t)(tB * 16 + n) * EDIM + q * 8;
#pragma unroll
      for (int kk = 0; kk < 4; ++kk) {
        b[2 * kk]     = *(const float4*)(bp + kk * 32);
        b[2 * kk + 1] = *(const float4*)(bp + kk * 32 + 4);
      }
    }
    if (hC) {
      const float* cp = Ct + (size_t)(tC * 16 + n) * EDIM + q * 8;
#pragma unroll
      for (int kk = 0; kk < 4; ++kk) {
        c[2 * kk]     = *(const float4*)(cp + kk * 32);
        c[2 * kk + 1] = *(const float4*)(cp + kk * 32 + 4);
      }
    }
    mfma_tile(a, Bhi, Blo, Dt, tA * 16, n, q);
    if (hB) mfma_tile(b, Bhi, Blo, Dt, tB * 16, n, q);
    if (hC) mfma_tile(c, Bhi, Blo, Dt, tC * 16, n, q);
  }
}

// ---------- heads unit (1 wave = 1 chunk-unit); h from LDS pool ----------
__device__ void do_heads(int unit, const float* h_lds,
                         const float* __restrict__ W1w, const float* __restrict__ W1b,
                         const float* __restrict__ W3w, const float* __restrict__ W3b,
                         const float* __restrict__ W4w, const float* __restrict__ W4b,
                         float* __restrict__ out, float* __restrict__ pbv,
                         int* __restrict__ pbi,
                         uint32_t k0a, uint32_t k0b, uint32_t k1a, uint32_t k1b,
                         uint32_t k2a, uint32_t k2b) {
  const int lane = threadIdx.x & 63;
  int head, b2, base, cnt, chunk, N;
  const float *W, *bias; size_t lg; uint32_t ka, kb;
  if (unit < 400)      { head = 1; b2 = unit / 25; chunk = unit % 25; base = chunk * 160; cnt = 160;
                         W = W3w; bias = W3b; N = 4000; lg = 64;     ka = k1a; kb = k1b; }
  else if (unit < 416) { head = 2; b2 = unit - 400; chunk = 0; base = 0; cnt = 200;
                         W = W4w; bias = W4b; N = 200;  lg = 128064; ka = k2a; kb = k2b; }
  else                 { head = 0; b2 = unit - 416; chunk = 0; base = 0; cnt = 2;
                         W = W1w; bias = W1b; N = 2;    lg = 0;      ka = k0a; kb = k0b; }
  const float4* hb4 = (const float4*)(h_lds + b2 * EDIM);
  float best = -INFINITY; int bi = 0x7FFFFFFF;
  for (int c = base + lane; c < base + cnt; c += 64) {
    const float4* wr = (const float4*)(W + (size_t)c * EDIM);
    float acc = bias[c];
#pragma unroll
    for (int i = 0; i < 32; ++i) {
      float4 w4 = wr[i], h4 = hb4[i];
      acc += w4.x * h4.x + w4.y * h4.y + w4.z * h4.z + w4.w * h4.w;
    }
    out[lg + (size_t)b2 * N + c] = acc;
    float g = acc + gumbel(ka, kb, (uint32_t)(b2 * N + c));
    if (g > best || (g == best && c < bi)) { best = g; bi = c; }
  }
#pragma unroll
  for (int off = 32; off > 0; off >>= 1) {
    float ov = __shfl_xor(best, off, 64);
    int oi = __shfl_xor(bi, off, 64);
    if (ov > best || (ov == best && oi < bi)) { best = ov; bi = oi; }
  }
  if (lane == 0) {
    scstore(pbv + (head * 16 + b2) * 25 + chunk, best);
    scstore_i(pbi + (head * 16 + b2) * 25 + chunk, bi);
  }
}

// ---------- lscat: blocks 0..63; Dt via sc-loads; exp -> wt atomics + psum ----------
__device__ void do_lscat(const int* __restrict__ story, const float* __restrict__ Dt,
                         float* __restrict__ wt, float* __restrict__ ps) {
  const int gt = blockIdx.x * TPB + threadIdx.x;   // < 32768
  const int lane = threadIdx.x & 63;
  const int b = gt >> 11, s = gt & 2047;
  int4 tk = ((const int4*)story)[b * SN + s];
  float l = scload(Dt + (size_t)tk.x * 16 + b) + scload(Dt + (size_t)tk.y * 16 + b)
          + scload(Dt + (size_t)tk.z * 16 + b) + scload(Dt + (size_t)tk.w * 16 + b);
  float e = expf(l);
  atomicAdd(&wt[(size_t)tk.x * 16 + b], e);
  atomicAdd(&wt[(size_t)tk.y * 16 + b], e);
  atomicAdd(&wt[(size_t)tk.z * 16 + b], e);
  atomicAdd(&wt[(size_t)tk.w * 16 + b], e);
  float sum = e;
#pragma unroll
  for (int off = 32; off > 0; off >>= 1) sum += __shfl_xor(sum, off, 64);
  if (lane == 0) scstore(ps + b * 32 + (s >> 6), sum);
}

// ---------- du-pass: depth-2 rows; wt via lane-split sc-load + shfl broadcast ----------
#define FMASH(CC, WV) {                                                   \
    _Pragma("unroll")                                                     \
    for (int b = 0; b < 16; ++b) {                                        \
      float wb_ = __shfl(WV, b, 64);                                      \
      acc[b].x += wb_ * CC.x; acc[b].y += wb_ * CC.y;                     \
    } }

__device__ void phase_du(const float* __restrict__ Ct, const float* __restrict__ wt,
                         float* __restrict__ dup, float* pool) {
  const int tid = threadIdx.x, bid = blockIdx.x;
  const int lane = tid & 63, w = tid >> 6;
  float2 acc[16];
#pragma unroll
  for (int b = 0; b < 16; ++b) acc[b] = make_float2(0.f, 0.f);
  const int r0 = bid * 392 + w * 49;
  int rn = VOCABN - r0;
  rn = rn < 0 ? 0 : (rn > 49 ? 49 : rn);
  float2 ccA, ccB; float wvA = 0.f, wvB = 0.f;
  if (rn > 0) {
    ccA = *(const float2*)(Ct + (size_t)r0 * EDIM + lane * 2);
    if (lane < 16) wvA = scload(wt + (size_t)r0 * 16 + lane);
  }
  if (rn > 1) {
    ccB = *(const float2*)(Ct + (size_t)(r0 + 1) * EDIM + lane * 2);
    if (lane < 16) wvB = scload(wt + (size_t)(r0 + 1) * 16 + lane);
  }
  int r = 0;
  for (; r + 2 < rn; r += 2) {
    FMASH(ccA, wvA);
    ccA = *(const float2*)(Ct + (size_t)(r0 + r + 2) * EDIM + lane * 2);
    if (lane < 16) wvA = scload(wt + (size_t)(r0 + r + 2) * 16 + lane);
    FMASH(ccB, wvB);
    int rv = (r + 3 < rn) ? (r0 + r + 3) : (r0 + r);   // guard: dummy reload
    ccB = *(const float2*)(Ct + (size_t)rv * EDIM + lane * 2);
    if (lane < 16) wvB = scload(wt + (size_t)rv * 16 + lane);
  }
  if (r < rn)     { FMASH(ccA, wvA); }
  if (r + 1 < rn) { FMASH(ccB, wvB); }
  // cross-wave tree reduce in LDS (stride-17 float2 per lane: conflict-free)
  float2* L = (float2*)pool;
  if (w >= 4) {
#pragma unroll
    for (int b = 0; b < 16; ++b) L[(w - 4) * 1088 + lane * 17 + b] = acc[b];
  }
  __syncthreads();
  if (w < 4) {
#pragma unroll
    for (int b = 0; b < 16; ++b) {
      float2 v = L[w * 1088 + lane * 17 + b];
      acc[b].x += v.x; acc[b].y += v.y;
    }
  }
  __syncthreads();
  if (w == 2 || w == 3) {
#pragma unroll
    for (int b = 0; b < 16; ++b) L[(w - 2) * 1088 + lane * 17 + b] = acc[b];
  }
  __syncthreads();
  if (w < 2) {
#pragma unroll
    for (int b = 0; b < 16; ++b) {
      float2 v = L[w * 1088 + lane * 17 + b];
      acc[b].x += v.x; acc[b].y += v.y;
    }
  }
  __syncthreads();
  if (w == 1) {
#pragma unroll
    for (int b = 0; b < 16; ++b) L[lane * 17 + b] = acc[b];
  }
  __syncthreads();
  if (w == 0) {
#pragma unroll
    for (int b = 0; b < 16; ++b) {
      float2 v = L[lane * 17 + b];
      acc[b].x += v.x; acc[b].y += v.y;
      scstore(dup + (size_t)bid * 2048 + b * EDIM + lane * 2,     acc[b].x);
      scstore(dup + (size_t)bid * 2048 + b * EDIM + lane * 2 + 1, acc[b].y);
    }
  }
}

// ---------- red: u_next[o] = u_prev[o] + (sum_p dup[p][o]) / S_b ----------
__device__ void phase_red(const float* __restrict__ dup, const float* __restrict__ ps,
                          const float* __restrict__ up, float* __restrict__ un) {
  const int lane = threadIdx.x & 63, w = threadIdx.x >> 6;
  const int o = blockIdx.x * 8 + w;           // 0..2047
  float t = scload(dup + (size_t)lane * 2048 + o)
          + scload(dup + (size_t)(lane + 64) * 2048 + o)
          + scload(dup + (size_t)(lane + 128) * 2048 + o)
          + scload(dup + (size_t)(lane + 192) * 2048 + o);
#pragma unroll
  for (int off = 32; off > 0; off >>= 1) t += __shfl_xor(t, off, 64);
  const int b = o >> 7;
  float sv = (lane < 32) ? scload(ps + b * 32 + lane) : 0.f;
#pragma unroll
  for (int off = 32; off > 0; off >>= 1) sv += __shfl_xor(sv, off, 64);
  if (lane == 0) scstore(un + o, scload(up + o) + t / sv);
}

// ---------- the mega-kernel ----------
__global__ void __launch_bounds__(TPB, 2)
k_mega(const int* __restrict__ story, const int* __restrict__ lengths,
       const float* __restrict__ hidden, const float* __restrict__ C,
       const float* __restrict__ Wm, const float* __restrict__ Wb,
       const float* __restrict__ W1w, const float* __restrict__ W1b,
       const float* __restrict__ W3w, const float* __restrict__ W3b,
       const float* __restrict__ W4w, const float* __restrict__ W4b,
       float* __restrict__ out, float* __restrict__ ws,
       uint32_t k0a, uint32_t k0b, uint32_t k1a, uint32_t k1b,
       uint32_t k2a, uint32_t k2b) {
  const int bid = blockIdx.x, tid = threadIdx.x;
  const int w = tid >> 6;
  const int gw = bid * 8 + w;
  __shared__ __align__(16) float pool[9216];   // 36 KB: h/u (D-phases) | du-tree

  uint32_t* ctr = (uint32_t*)(ws + CTR_OFF);
  float* ps  = ws + PS_OFF;
  float* u0g = ws + U0_OFF;
  float* u1g = ws + U1_OFF;
  float* u2g = ws + U2_OFF;
  float* pbv = ws + PBV_OFF;
  int*   pbi = (int*)(ws + PBI_OFF);
  float* Dt  = ws + DT_OFF;
  float* wt  = ws + WT_OFF;
  float* dup = ws + DUP_OFF;
  const float* C0 = C;
  const float* C1 = C + (size_t)1 * VOCABN * EDIM;
  const float* C2 = C + (size_t)2 * VOCABN * EDIM;

  // --- P0: every block computes h = hidden@Wm^T+Wb into LDS (identical copies) ---
  for (int i = tid; i < 2048; i += TPB) {
    int b = i >> 7, j = i & 127;
    const float4* wr = (const float4*)(Wm + (size_t)j * EDIM);
    const float4* hr = (const float4*)(hidden + (size_t)b * EDIM);
    float acc = Wb[j];
#pragma unroll
    for (int q2 = 0; q2 < 32; ++q2) {
      float4 w4 = wr[q2], h4 = hr[q2];
      acc += w4.x * h4.x + w4.y * h4.y + w4.z * h4.z + w4.w * h4.w;
    }
    pool[i] = acc;
  }
  __syncthreads();
  if (tid < 8) scstore(u0g + bid * 8 + tid, pool[bid * 8 + tid]);  // slice for P4

  // --- P1: zero wt + heads + D0 = C0 . u0 ---
  if (gw < 432)
    do_heads(gw, pool, W1w, W1b, W3w, W3b, W4w, W4b, out, pbv, pbi,
             k0a, k0b, k1a, k1b, k2a, k2b);
  phase_D(C0, pool, Dt, wt, gw);
  gbar(ctr + 0);

  // --- P2: lscat hop0 (blocks 0..63) + one-hots (blocks 64..195) ---
  if (bid < 64) {
    do_lscat(story, Dt, wt, ps);
  } else if (bid < 196) {
    int g = (bid - 64) * TPB + tid;
    if (g < 67232) {
      int head, b2, c; size_t off; int nch;
      if (g < 64000)      { head = 1; b2 = g / 4000; c = g % 4000; off = 64064 + g;          nch = 25; }
      else if (g < 67200) { int gg = g - 64000; head = 2; b2 = gg / 200; c = gg % 200; off = 131264 + gg; nch = 1; }
      else                { int gg = g - 67200; head = 0; b2 = gg >> 1; c = gg & 1;   off = 32 + gg;     nch = 1; }
      float bv = -INFINITY; int bi2 = 0x7FFFFFFF;
      for (int ch = 0; ch < nch; ++ch) {
        float v = scload(pbv + (head * 16 + b2) * 25 + ch);
        int i2 = scload_i(pbi + (head * 16 + b2) * 25 + ch);
        if (v > bv || (v == bv && i2 < bi2)) { bv = v; bi2 = i2; }
      }
      out[off] = (c == bi2) ? 1.0f : 0.0f;
    }
  }
  gbar(ctr + 1);

  // --- P3: du0 partials over C1 ---
  phase_du(C1, wt, dup, pool);
  gbar(ctr + 2);

  // --- P4: u1 = u0 + du0/S0 ; re-zero wt ---
  phase_red(dup, ps, u0g, u1g);
  for (int i = bid * TPB + tid; i < VOCABN * 16; i += GRID * TPB) scstore(wt + i, 0.f);
  gbar(ctr + 3);

  // --- P5: D1 = C1 . u1 ---
  load_u_lds(u1g, pool);
  phase_D(C1, pool, Dt, nullptr, gw);
  gbar(ctr + 4);

  // --- P6: lscat hop1 ---
  if (bid < 64) do_lscat(story, Dt, wt, ps);
  gbar(ctr + 5);

  // --- P7: du1 partials over C2 ---
  phase_du(C2, wt, dup, pool);
  gbar(ctr + 6);

  // --- P8: u2 = u1 + du1/S1 ---
  phase_red(dup, ps, u1g, u2g);
  gbar(ctr + 7);

  // --- P9: D2 = C2 . u2 ---
  load_u_lds(u2g, pool);
  phase_D(C2, pool, Dt, nullptr, gw);
  gbar(ctr + 8);

  // --- P10: final logits -> masked sigmoid ---
  {
    const int gt = bid * TPB + tid;
    if (gt < 32768) {
      const int b = gt >> 11, s = gt & 2047;
      int4 tk = ((const int4*)story)[b * SN + s];
      float l = scload(Dt + (size_t)tk.x * 16 + b) + scload(Dt + (size_t)tk.y * 16 + b)
              + scload(Dt + (size_t)tk.z * 16 + b) + scload(Dt + (size_t)tk.w * 16 + b);
      int len = lengths[b];
      out[134464 + (size_t)b * SN + s] = (s < len) ? 1.0f / (1.0f + expf(-l)) : 0.0f;
    }
  }
}

extern "C" void kernel_launch(void* const* d_in, const int* in_sizes, int n_in,
                              void* d_out, int out_size, void* d_ws, size_t ws_size,
                              hipStream_t stream) {
  const int *story = nullptr, *lengths = nullptr;
  const float *hidden = nullptr, *C = nullptr, *Wm = nullptr, *Wb = nullptr,
              *W1w = nullptr, *W1b = nullptr, *W3w = nullptr, *W3b = nullptr,
              *W4w = nullptr, *W4b = nullptr;
  for (int i = 0; i < n_in; ++i) {
    switch (in_sizes[i]) {
      case 16 * 2048 * 4:    story   = (const int*)d_in[i]; break;
      case 16:               lengths = (const int*)d_in[i]; break;
      case 16 * 128:         hidden  = (const float*)d_in[i]; break;
      case 4 * 100000 * 128: C       = (const float*)d_in[i]; break;
      case 128 * 128:        Wm      = (const float*)d_in[i]; break;
      case 128:              Wb      = (const float*)d_in[i]; break;
      case 2 * 128:          W1w     = (const float*)d_in[i]; break;
      case 2:                W1b     = (const float*)d_in[i]; break;
      case 4000 * 128:       W3w     = (const float*)d_in[i]; break;
      case 4000:             W3b     = (const float*)d_in[i]; break;
      case 200 * 128:        W4w     = (const float*)d_in[i]; break;
      case 200:              W4b     = (const float*)d_in[i]; break;
      default: break;
    }
  }
  float* out = (float*)d_out;
  float* ws  = (float*)d_ws;

  uint32_t k0a, k0b, k1a, k1b, k2a, k2b;
  tf2x32(0u, 42u, 0u, 0u, &k0a, &k0b);
  tf2x32(0u, 42u, 0u, 1u, &k1a, &k1b);
  tf2x32(0u, 42u, 0u, 2u, &k2a, &k2b);

  hipMemsetAsync(d_ws, 0, 64, stream);   // zero the 9 barrier counters

  void* args[] = {(void*)&story, (void*)&lengths, (void*)&hidden, (void*)&C,
                  (void*)&Wm, (void*)&Wb, (void*)&W1w, (void*)&W1b,
                  (void*)&W3w, (void*)&W3b, (void*)&W4w, (void*)&W4b,
                  (void*)&out, (void*)&ws,
                  (void*)&k0a, (void*)&k0b, (void*)&k1a, (void*)&k1b,
                  (void*)&k2a, (void*)&k2b};
  hipLaunchCooperativeKernel((const void*)k_mega, dim3(GRID), dim3(TPB),
                             args, 0, stream);
}

// Round 12
// 328.481 us; speedup vs baseline: 1.5982x; 1.5982x over previous
//
#include <hip/hip_runtime.h>
#include <hip/hip_bf16.h>
#include <stdint.h>

typedef __hip_bfloat16 bf16;

#define VOCABN 100000
#define EDIM 128
#define BN 16
#define SN 2048

// ws float offsets (R1-champion layout)
#define H_OFF    0         // u1 (hop0 output u) -- was h in R1; h now lives in LDS
#define U_OFF    2048      // u0
#define L0_OFF   4096      // 32768 floats (row buffer: l0, then l1 in place)
#define DUP_OFF  36864     // 16*16*128 = 32768 floats (partial du)
#define PBV_OFF  69648     // 1200
#define PBI_OFF  70848     // 1200
#define G_OFF    73728     // uint32 region: 2 tables * 16*2048*64 = 4194304 u32 (16 MB)

// ---------- threefry2x32 (JAX partitionable) ----------
__host__ __device__ inline void tf2x32(uint32_t k0, uint32_t k1,
                                       uint32_t x0, uint32_t x1,
                                       uint32_t* o0, uint32_t* o1) {
  const uint32_t rotA[4] = {13u, 15u, 26u, 6u};
  const uint32_t rotB[4] = {17u, 29u, 16u, 24u};
  uint32_t ks0 = k0, ks1 = k1, ks2 = k0 ^ k1 ^ 0x1BD11BDAu;
  x0 += ks0; x1 += ks1;
#pragma unroll
  for (int g = 0; g < 5; ++g) {
    const uint32_t* r = (g & 1) ? rotB : rotA;
#pragma unroll
    for (int i = 0; i < 4; ++i) {
      x0 += x1;
      x1 = (x1 << r[i]) | (x1 >> (32u - r[i]));
      x1 ^= x0;
    }
    uint32_t a0 = (g % 3 == 0) ? ks1 : ((g % 3 == 1) ? ks2 : ks0);
    uint32_t a1 = (g % 3 == 0) ? ks2 : ((g % 3 == 1) ? ks0 : ks1);
    x0 += a0;
    x1 += a1 + (uint32_t)(g + 1);
  }
  *o0 = x0; *o1 = x1;
}

__device__ inline float blo(uint32_t v) { return __uint_as_float(v << 16); }
__device__ inline float bhi(uint32_t v) { return __uint_as_float(v & 0xffff0000u); }
__device__ inline uint16_t f2bu(float f) {
  bf16 h = __float2bfloat16(f);
  uint16_t u; __builtin_memcpy(&u, &h, 2); return u;
}
__device__ inline float gumbel(uint32_t ka, uint32_t kb, uint32_t flat) {
  uint32_t o0, o1;
  tf2x32(ka, kb, 0u, flat, &o0, &o1);
  uint32_t bits = o0 ^ o1;
  float u0 = __uint_as_float((bits >> 9) | 0x3f800000u) - 1.0f;
  float uu = fmaxf(1e-10f, u0 + 1e-10f);
  return -logf(-logf(uu));
}

// ---------- heads: in-block h = hidden@Wm^T+Wb (R7-proven); logits; gumbel partials ----------
// 16 designated blocks (head1, chunk0) persist h as u0 for the memory hops.
__global__ void k_heads(const float* __restrict__ hidden,
                        const float* __restrict__ Wm, const float* __restrict__ Wb,
                        const float* __restrict__ W1w, const float* __restrict__ W1b,
                        const float* __restrict__ W3w, const float* __restrict__ W3b,
                        const float* __restrict__ W4w, const float* __restrict__ W4b,
                        float* __restrict__ out, float* __restrict__ pbv,
                        int* __restrict__ pbi, float* __restrict__ u0,
                        uint32_t k0a, uint32_t k0b, uint32_t k1a, uint32_t k1b,
                        uint32_t k2a, uint32_t k2b) {
  int bid = blockIdx.x, tid = threadIdx.x;
  __shared__ float hb[EDIM];
  __shared__ float sv[256];
  __shared__ int si[256];
  int head, b2, base, cnt, chunk, N;
  const float *W, *bias; size_t lg_off; uint32_t ka, kb;
  if (bid < 400)      { head = 1; b2 = bid / 25; chunk = bid % 25; base = chunk * 160; cnt = 160;
                        W = W3w; bias = W3b; N = 4000; lg_off = 64;     ka = k1a; kb = k1b; }
  else if (bid < 416) { head = 2; b2 = bid - 400; chunk = 0; base = 0; cnt = 200;
                        W = W4w; bias = W4b; N = 200;  lg_off = 128064; ka = k2a; kb = k2b; }
  else                { head = 0; b2 = bid - 416; chunk = 0; base = 0; cnt = 2;
                        W = W1w; bias = W1b; N = 2;    lg_off = 0;      ka = k0a; kb = k0b; }
  if (tid < 128) {
    const float4* wr = (const float4*)(Wm + (size_t)tid * EDIM);
    const float4* hr = (const float4*)(hidden + (size_t)b2 * EDIM);
    float acc = Wb[tid];
#pragma unroll
    for (int i = 0; i < 32; ++i) {
      float4 w4 = wr[i], h4 = hr[i];
      acc += w4.x * h4.x + w4.y * h4.y + w4.z * h4.z + w4.w * h4.w;
    }
    hb[tid] = acc;
    if (bid < 400 && (bid % 25) == 0) u0[b2 * EDIM + tid] = acc;
  }
  __syncthreads();
  float best = -INFINITY; int bi = 0x7FFFFFFF;
  if (tid < cnt) {
    int c = base + tid;
    const float4* wr = (const float4*)(W + (size_t)c * EDIM);
    const float4* hb4 = (const float4*)hb;
    float acc = bias[c];
#pragma unroll
    for (int i = 0; i < 32; ++i) {
      float4 w4 = wr[i], h4 = hb4[i];
      acc += w4.x * h4.x + w4.y * h4.y + w4.z * h4.z + w4.w * h4.w;
    }
    out[lg_off + (size_t)b2 * N + c] = acc;
    best = acc + gumbel(ka, kb, (uint32_t)(b2 * N + c));
    bi = c;
  }
  sv[tid] = best; si[tid] = bi;
  __syncthreads();
  for (int s2 = 128; s2 > 0; s2 >>= 1) {
    if (tid < s2) {
      float ov = sv[tid + s2]; int oi = si[tid + s2];
      if (ov > sv[tid] || (ov == sv[tid] && oi < si[tid])) { sv[tid] = ov; si[tid] = oi; }
    }
    __syncthreads();
  }
  if (tid == 0) {
    pbv[(head * 16 + b2) * 25 + chunk] = sv[0];
    pbi[(head * 16 + b2) * 25 + chunk] = si[0];
  }
}

// ---------- gather (+ one-hot blocks): t=0 -> l0 (f32 dot with u); t=1,2 -> bf16 G ----------
// blocks [0,24576): gather; blocks [24576,24839): one-hot scan (champion k_onehot).
__global__ void k_gather_l0(const int* __restrict__ story, const float* __restrict__ C,
                            const float* __restrict__ u, uint32_t* __restrict__ G,
                            float* __restrict__ l0,
                            const float* __restrict__ pbv, const int* __restrict__ pbi,
                            float* __restrict__ out) {
  const int bid = blockIdx.x;
  if (bid >= 24576) {
    int g = (bid - 24576) * 256 + threadIdx.x;
    if (g >= 67232) return;
    int head, b2, c; size_t off; int nch;
    if (g < 64000)      { head = 1; b2 = g / 4000; c = g % 4000; off = 64064 + g;          nch = 25; }
    else if (g < 67200) { int gg = g - 64000; head = 2; b2 = gg / 200; c = gg % 200; off = 131264 + gg; nch = 1; }
    else                { int gg = g - 67200; head = 0; b2 = gg >> 1; c = gg & 1;   off = 32 + gg;     nch = 1; }
    float bv = -INFINITY; int bi = 0x7FFFFFFF;
    for (int ch = 0; ch < nch; ++ch) {
      float v = pbv[(head * 16 + b2) * 25 + ch];
      int i2 = pbi[(head * 16 + b2) * 25 + ch];
      if (v > bv || (v == bv && i2 < bi)) { bv = v; bi = i2; }
    }
    out[off] = (c == bi) ? 1.0f : 0.0f;
    return;
  }
  int wid = (bid << 2) | (threadIdx.x >> 6);  // 0..98303
  int lane = threadIdx.x & 63;
  int t = wid >> 15;
  int bs = wid & 32767;
  int4 idx = ((const int4*)story)[bs];
  const float2* r0 = (const float2*)(C + ((size_t)t * VOCABN + idx.x) * EDIM);
  const float2* r1 = (const float2*)(C + ((size_t)t * VOCABN + idx.y) * EDIM);
  const float2* r2 = (const float2*)(C + ((size_t)t * VOCABN + idx.z) * EDIM);
  const float2* r3 = (const float2*)(C + ((size_t)t * VOCABN + idx.w) * EDIM);
  float2 a = r0[lane], b = r1[lane], c = r2[lane], d = r3[lane];
  float lo = a.x + b.x + c.x + d.x;
  float hi = a.y + b.y + c.y + d.y;
  if (t == 0) {
    float2 uu = ((const float2*)(u + ((bs >> 11) << 7)))[lane];
    float s = lo * uu.x + hi * uu.y;
#pragma unroll
    for (int off = 32; off > 0; off >>= 1) s += __shfl_xor(s, off, 64);
    if (lane == 0) l0[bs] = s;
  } else {
    G[((size_t)(t - 1) * BN * SN + bs) * 64 + lane] =
        (uint32_t)f2bu(lo) | ((uint32_t)f2bu(hi) << 16);
  }
}

// ---------- hop phase B: per-slice softmax-weighted partial du (R1-champion) ----------
__global__ void __launch_bounds__(256) k_hopB(const uint32_t* __restrict__ Gt,
                                              const float* __restrict__ row_in,
                                              float* __restrict__ dup) {
  const int b = blockIdx.x >> 4, k = blockIdx.x & 15;
  const int tid = threadIdx.x, wave = tid >> 6, lane = tid & 63;
  __shared__ float sr[SN];
  __shared__ float red[4];
  __shared__ float acc[4][EDIM];

  const float4* rin = (const float4*)(row_in + (size_t)b * SN);
  float4* sr4 = (float4*)sr;
  for (int i = tid; i < SN / 4; i += 256) sr4[i] = rin[i];
  __syncthreads();

  float m = -INFINITY;
  for (int i = tid; i < SN; i += 256) m = fmaxf(m, sr[i]);
#pragma unroll
  for (int off = 32; off > 0; off >>= 1) m = fmaxf(m, __shfl_xor(m, off, 64));
  if (lane == 0) red[wave] = m;
  __syncthreads();
  m = fmaxf(fmaxf(red[0], red[1]), fmaxf(red[2], red[3]));

  float s = 0.f;
  for (int i = tid; i < SN; i += 256) s += expf(sr[i] - m);
#pragma unroll
  for (int off = 32; off > 0; off >>= 1) s += __shfl_xor(s, off, 64);
  __syncthreads();
  if (lane == 0) red[wave] = s;
  __syncthreads();
  float invS = 1.0f / (red[0] + red[1] + red[2] + red[3]);

  const uint32_t* Gb = Gt + (size_t)b * SN * 64;
  int sub = lane >> 4, le = lane & 15;
  float a[8] = {0, 0, 0, 0, 0, 0, 0, 0};
#pragma unroll
  for (int it = 0; it < 8; ++it) {
    int cell = k * 128 + wave * 32 + it * 4 + sub;
    uint4 v = *(const uint4*)(Gb + (size_t)cell * 64 + le * 4);
    float pp = expf(sr[cell] - m);
    a[0] += blo(v.x) * pp; a[1] += bhi(v.x) * pp;
    a[2] += blo(v.y) * pp; a[3] += bhi(v.y) * pp;
    a[4] += blo(v.z) * pp; a[5] += bhi(v.z) * pp;
    a[6] += blo(v.w) * pp; a[7] += bhi(v.w) * pp;
  }
#pragma unroll
  for (int j = 0; j < 8; ++j) {
    a[j] += __shfl_xor(a[j], 16, 64);
    a[j] += __shfl_xor(a[j], 32, 64);
  }
  if (lane < 16) {
#pragma unroll
    for (int j = 0; j < 8; ++j) acc[wave][lane * 8 + j] = a[j];
  }
  __syncthreads();
  if (tid < EDIM) {
    float d = (acc[0][tid] + acc[1][tid] + acc[2][tid] + acc[3][tid]) * invS;
    dup[((size_t)b * 16 + k) * EDIM + tid] = d;
  }
}

// ---------- hop phase C: u_new = u_in + sum_k dup; logits (or final sigmoid) ----------
__global__ void __launch_bounds__(256) k_hopC(const uint32_t* __restrict__ Gt,
                                              const float* __restrict__ dup,
                                              const float* __restrict__ u_in,
                                              float* __restrict__ u_out,
                                              float* __restrict__ row_out,
                                              const int* __restrict__ lengths,
                                              float* __restrict__ out) {
  const int b = blockIdx.x >> 4, k = blockIdx.x & 15;
  const int tid = threadIdx.x, wave = tid >> 6, lane = tid & 63;
  __shared__ float u_l[EDIM];
  if (tid < EDIM) {
    float v = u_in[b * EDIM + tid];
    const float* dp = dup + (size_t)b * 16 * EDIM + tid;
#pragma unroll
    for (int kk = 0; kk < 16; ++kk) v += dp[kk * EDIM];
    u_l[tid] = v;
    if (u_out != nullptr && k == 0) u_out[b * EDIM + tid] = v;
  }
  __syncthreads();

  const uint32_t* Gb = Gt + (size_t)b * SN * 64;
  int sub = lane >> 4, le = lane & 15;
  const float4* u4 = (const float4*)u_l;
  float4 ua = u4[le * 2], ub = u4[le * 2 + 1];
  int len = (lengths != nullptr) ? lengths[b] : 0;
#pragma unroll
  for (int it = 0; it < 8; ++it) {
    int cell = k * 128 + wave * 32 + it * 4 + sub;
    uint4 v = *(const uint4*)(Gb + (size_t)cell * 64 + le * 4);
    float s = blo(v.x) * ua.x + bhi(v.x) * ua.y + blo(v.y) * ua.z + bhi(v.y) * ua.w
            + blo(v.z) * ub.x + bhi(v.z) * ub.y + blo(v.w) * ub.z + bhi(v.w) * ub.w;
#pragma unroll
    for (int off = 8; off > 0; off >>= 1) s += __shfl_xor(s, off, 64);
    if (le == 0) {
      if (row_out != nullptr) {
        row_out[(size_t)b * SN + cell] = s;
      } else {
        out[134464 + (size_t)b * SN + cell] =
            (cell < len) ? 1.0f / (1.0f + expf(-s)) : 0.0f;
      }
    }
  }
}

extern "C" void kernel_launch(void* const* d_in, const int* in_sizes, int n_in,
                              void* d_out, int out_size, void* d_ws, size_t ws_size,
                              hipStream_t stream) {
  const int *story = nullptr, *lengths = nullptr;
  const float *hidden = nullptr, *C = nullptr, *Wm = nullptr, *Wb = nullptr,
              *W1w = nullptr, *W1b = nullptr, *W3w = nullptr, *W3b = nullptr,
              *W4w = nullptr, *W4b = nullptr;
  for (int i = 0; i < n_in; ++i) {
    switch (in_sizes[i]) {
      case 16 * 2048 * 4:    story   = (const int*)d_in[i]; break;
      case 16:               lengths = (const int*)d_in[i]; break;
      case 16 * 128:         hidden  = (const float*)d_in[i]; break;
      case 4 * 100000 * 128: C       = (const float*)d_in[i]; break;
      case 128 * 128:        Wm      = (const float*)d_in[i]; break;
      case 128:              Wb      = (const float*)d_in[i]; break;
      case 2 * 128:          W1w     = (const float*)d_in[i]; break;
      case 2:                W1b     = (const float*)d_in[i]; break;
      case 4000 * 128:       W3w     = (const float*)d_in[i]; break;
      case 4000:             W3b     = (const float*)d_in[i]; break;
      case 200 * 128:        W4w     = (const float*)d_in[i]; break;
      case 200:              W4b     = (const float*)d_in[i]; break;
      default: break;
    }
  }
  float* out = (float*)d_out;
  float* ws  = (float*)d_ws;
  float* u1  = ws + H_OFF;       // hop0 output u (was h region in R1)
  float* u0  = ws + U_OFF;
  float* row = ws + L0_OFF;      // l0, then l1 in place
  float* dup = ws + DUP_OFF;
  float* pbv = ws + PBV_OFF;
  int*   pbi = (int*)(ws + PBI_OFF);
  uint32_t* G = (uint32_t*)(ws + G_OFF);
  const size_t TSZ = (size_t)BN * SN * 64;   // u32 per G table

  uint32_t k0a, k0b, k1a, k1b, k2a, k2b;
  tf2x32(0u, 42u, 0u, 0u, &k0a, &k0b);
  tf2x32(0u, 42u, 0u, 1u, &k1a, &k1b);
  tf2x32(0u, 42u, 0u, 2u, &k2a, &k2b);

  // 1) heads (computes h in-block; persists u0)
  k_heads<<<432, 256, 0, stream>>>(hidden, Wm, Wb, W1w, W1b, W3w, W3b, W4w, W4b,
                                   out, pbv, pbi, u0,
                                   k0a, k0b, k1a, k1b, k2a, k2b);
  // 2) gather (l0 + bf16 G tables) + one-hot blocks appended to the grid
  k_gather_l0<<<24576 + 263, 256, 0, stream>>>(story, C, u0, G, row, pbv, pbi, out);
  // 3-4) hop 0: softmax(l0) -> du partials over G[0]; u1 = u0 + du; l1 = G[0]·u1
  k_hopB<<<BN * 16, 256, 0, stream>>>(G, row, dup);
  k_hopC<<<BN * 16, 256, 0, stream>>>(G, dup, u0, /*u_out=*/u1, /*row_out=*/row,
                                      nullptr, out);
  // 5-6) hop 1: softmax(l1) -> du partials over G[1]; u2 = u1 + du;
  //      final logits G[1]·u2 -> masked sigmoid into out
  k_hopB<<<BN * 16, 256, 0, stream>>>(G + TSZ, row, dup);
  k_hopC<<<BN * 16, 256, 0, stream>>>(G + TSZ, dup, /*u_in=*/u1, nullptr, nullptr,
                                      lengths, out);
}